// Round 9
// baseline (129.233 us; speedup 1.0000x reference)
//
#include <hip/hip_runtime.h>
#include <hip/hip_bf16.h>

typedef __attribute__((ext_vector_type(8))) short short8;
typedef __attribute__((ext_vector_type(8))) _Float16 half8;
typedef __attribute__((ext_vector_type(2))) _Float16 h2;
typedef __attribute__((ext_vector_type(4))) float f32x4;

#define NFACE 16384
#define NBATCH 8
#define CIN 128
#define COUT 128
#define KGEMM 512
#define FBLK 64                        // faces per block (2 face-waves x 32)
#define GRID ((NBATCH * NFACE) / FBLK) // 2048, divisible by 8

__device__ __forceinline__ unsigned short f2bf(float x) {
    union { float f; unsigned u; } v; v.f = x;
    unsigned r = v.u + 0x7fffu + ((v.u >> 16) & 1u);  // RNE
    return (unsigned short)(r >> 16);
}
__device__ __forceinline__ unsigned pack2bf(float lo, float hi) {
    return (unsigned)f2bf(lo) | ((unsigned)f2bf(hi) << 16);
}
__device__ __forceinline__ h2 habs2(h2 x) {
    union { h2 h; unsigned u; } v; v.h = x; v.u &= 0x7fff7fffu; return v.h;
}
__device__ __forceinline__ unsigned h2u(h2 x) {
    union { h2 h; unsigned u; } v; v.h = x; return v.u;
}
__device__ __forceinline__ h2 u2h(unsigned x) {
    union { h2 h; unsigned u; } v; v.u = x; return v.h;
}

// ---- features fp32 -> packed f16 (linear grid) ----
__global__ void fconv_kernel(const float* __restrict__ f, unsigned* __restrict__ o, int n4) {
    int i = blockIdx.x * 256 + threadIdx.x;  // one uint4 (8 floats -> 8 halfs)
    if (i >= n4) return;
    const float4* fp = (const float4*)f;
    float4 a = fp[i * 2], b = fp[i * 2 + 1];
    h2 p0 = {(_Float16)a.x, (_Float16)a.y};
    h2 p1 = {(_Float16)a.z, (_Float16)a.w};
    h2 p2 = {(_Float16)b.x, (_Float16)b.y};
    h2 p3 = {(_Float16)b.z, (_Float16)b.w};
    uint4 r; r.x = h2u(p0); r.y = h2u(p1); r.z = h2u(p2); r.w = h2u(p3);
    ((uint4*)o)[i] = r;
}

// ---- weight fp32 (o,c,1,4) -> f16, chunked kk-major K: wbt2[o][ (c>>5)*128 + kk*32 + (c&31) ] ----
__global__ void wconv2_kernel(const float* __restrict__ w, _Float16* __restrict__ bt2) {
    int i = blockIdx.x * 256 + threadIdx.x;  // one (o,c) pair = 4 floats
    if (i >= COUT * CIN) return;
    int o = i >> 7, c = i & 127;
    float4 wv = ((const float4*)w)[i];
    _Float16* dst = bt2 + (size_t)o * KGEMM + (c >> 5) * 128 + (c & 31);
    dst[0]  = (_Float16)wv.x;
    dst[32] = (_Float16)wv.y;
    dst[64] = (_Float16)wv.z;
    dst[96] = (_Float16)wv.w;
}

// ---- old-layout bf16 weight (fallback path): bt[o][kk*128+c] ----
__global__ void wconv_kernel(const float* __restrict__ w, unsigned short* __restrict__ bt) {
    int i = blockIdx.x * 256 + threadIdx.x;
    if (i >= COUT * CIN) return;
    int o = i >> 7, c = i & 127;
#pragma unroll
    for (int kk = 0; kk < 4; ++kk)
        bt[o * KGEMM + kk * CIN + c] = f2bf(w[(o * CIN + c) * 4 + kk]);
}

// Build the 4 A-fragments (kk=0..3) for one face's 8-channel octet, in registers.
// Lane (lo,hi) computes channels [hi*8, hi*8+8) of chunk ch — exactly the MFMA
// A-fragment k-slice [hi*8, hi*8+8) for each kk (kk-major K layout).
struct AFrag { half8 f[4]; };
__device__ __forceinline__ AFrag build_reg(const char* __restrict__ fbb, int off, int ch) {
    uint4 n0 = *(const uint4*)(fbb + off);  // off already includes neighbor 0... (see caller)
    AFrag r; (void)n0; return r;            // placeholder (unused; real one below)
}

__device__ __forceinline__ AFrag build_frag(const char* __restrict__ fbb,
                                            const int* __restrict__ offs,  // 6 byte-offsets (face*256+hi*16)
                                            int ch) {
    uint4 n[6];
#pragma unroll
    for (int j = 0; j < 6; ++j)
        n[j] = *(const uint4*)(fbb + (size_t)(offs[j] + ch * 64));

    unsigned f1w[4], f2w[4], f3w[4];
#pragma unroll
    for (int q = 0; q < 4; ++q) {  // q = word = channels 2q,2q+1
        h2 x0 = u2h(((const unsigned*)&n[0])[q]);
        h2 x1 = u2h(((const unsigned*)&n[1])[q]);
        h2 x2 = u2h(((const unsigned*)&n[2])[q]);
        h2 x3 = u2h(((const unsigned*)&n[3])[q]);
        h2 x4 = u2h(((const unsigned*)&n[4])[q]);
        h2 x5 = u2h(((const unsigned*)&n[5])[q]);
        h2 s = x1 + x2; s = s + x3; s = s + x4; s = s + x5;
        h2 five = {(_Float16)5.0f, (_Float16)5.0f};
        h2 d = habs2(five * x0 - s);
        h2 t3 = habs2(x1 - x2) + habs2(x1 - x3);
        t3 = t3 + habs2(x1 - x4); t3 = t3 + habs2(x1 - x5);
        t3 = t3 + habs2(x2 - x3); t3 = t3 + habs2(x2 - x4);
        t3 = t3 + habs2(x2 - x5); t3 = t3 + habs2(x3 - x4);
        t3 = t3 + habs2(x3 - x5); t3 = t3 + habs2(x4 - x5);
        f1w[q] = h2u(s); f2w[q] = h2u(d); f3w[q] = h2u(t3);
    }
    AFrag r;
    *(uint4*)&r.f[0] = n[0];
    *(uint4*)&r.f[1] = (uint4){f1w[0], f1w[1], f1w[2], f1w[3]};
    *(uint4*)&r.f[2] = (uint4){f2w[0], f2w[1], f2w[2], f2w[3]};
    *(uint4*)&r.f[3] = (uint4){f3w[0], f3w[1], f3w[2], f3w[3]};
    return r;
}

// v9: barrier-free, LDS-free (except ridx stage). A-fragments built in registers
// (lane (lo,hi) builds exactly its MFMA A k-slice); B-fragments read directly
// from L2-resident 128 KiB weight. Wave = 32 faces x 64 cols, fully independent.
__global__ __launch_bounds__(256, 3)
void meshconv_v9(const unsigned* __restrict__ featf16,
                 const int* __restrict__ ring,
                 const _Float16* __restrict__ wbt2,
                 const float* __restrict__ bias,
                 float* __restrict__ out)
{
    __shared__ int ridx[FBLK * 6];  // 1.5 KiB

    const int t = threadIdx.x;
    // batch-per-XCD swizzle: 256 blocks per batch, one batch per XCD
    const int bid = (blockIdx.x & 7) * (GRID / 8) + (blockIdx.x >> 3);
    const int base = bid * FBLK;
    const int batch = bid >> 8;   // 256 blocks per batch

    if (t < 96)  // 64 faces * 6 ints = 96 uint4
        ((uint4*)ridx)[t] = ((const uint4*)(ring + (size_t)base * 6))[t];
    __syncthreads();  // the only barrier

    const int w   = t >> 6;   // 4 waves: 2 face-groups x 2 col-halves
    const int l   = t & 63;
    const int lo  = l & 15;
    const int hi  = l >> 4;
    const int wf  = w >> 1;   // face group: faces [wf*32, wf*32+32)
    const int wcg = w & 1;    // col half:   cols  [wcg*64, wcg*64+64)
    const int col0 = wcg * 64;

    const char* __restrict__ fbb = (const char*)featf16 + (size_t)batch * NFACE * 256;

    // Per-lane neighbor byte-offsets for its two faces (reused all 4 chunks).
    int offA[6], offB[6];
    {
        const int* riA = &ridx[(wf * 32 + lo) * 6];
        const int* riB = &ridx[(wf * 32 + 16 + lo) * 6];
#pragma unroll
        for (int j = 0; j < 6; ++j) {
            offA[j] = riA[j] * 256 + hi * 16;
            offB[j] = riB[j] * 256 + hi * 16;
        }
    }

    f32x4 acc[2][4];
#pragma unroll
    for (int rt = 0; rt < 2; ++rt)
#pragma unroll
        for (int ct = 0; ct < 4; ++ct)
            acc[rt][ct] = (f32x4){0.f, 0.f, 0.f, 0.f};

    // B base: lane reads col = col0 + ct*16 + lo, k = ch*128 + ks*32 + hi*8
    const _Float16* __restrict__ wb = wbt2 + (size_t)(col0 + lo) * KGEMM + hi * 8;

#pragma unroll
    for (int ch = 0; ch < 4; ++ch) {
        AFrag a0 = build_frag(fbb, offA, ch);
        AFrag a1 = build_frag(fbb, offB, ch);

#pragma unroll
        for (int ks = 0; ks < 4; ++ks) {
#pragma unroll
            for (int ct = 0; ct < 4; ++ct) {
                half8 b = *(const half8*)&wb[(size_t)(ct * 16) * KGEMM + ch * 128 + ks * 32];
                acc[0][ct] = __builtin_amdgcn_mfma_f32_16x16x32_f16(a0.f[ks], b, acc[0][ct], 0, 0, 0);
                acc[1][ct] = __builtin_amdgcn_mfma_f32_16x16x32_f16(a1.f[ks], b, acc[1][ct], 0, 0, 0);
            }
        }
    }

    // ---- epilogue: + bias, store fp32 ----
    float bo[4];
#pragma unroll
    for (int ct = 0; ct < 4; ++ct) bo[ct] = bias[col0 + ct * 16 + lo];
#pragma unroll
    for (int rt = 0; rt < 2; ++rt) {
#pragma unroll
        for (int ct = 0; ct < 4; ++ct) {
#pragma unroll
            for (int v = 0; v < 4; ++v) {
                const int r = base + wf * 32 + rt * 16 + hi * 4 + v;  // C/D: row=(l>>4)*4+v, col=l&15
                out[(size_t)r * COUT + col0 + ct * 16 + lo] = acc[rt][ct][v] + bo[ct];
            }
        }
    }
}

// fallback (ws too small): fp32 gather, bf16 MFMA, old weight layout
__global__ __launch_bounds__(256, 4)
void meshconv_ref(const float* __restrict__ feat,
                  const int* __restrict__ ring,
                  const unsigned short* __restrict__ wbt,
                  const float* __restrict__ bias,
                  float* __restrict__ out)
{
#define RMBLK 32
#define RLDF 520
    __shared__ unsigned short fcv[RMBLK * RLDF];
    __shared__ int ridx[RMBLK * 6];

    const int t = threadIdx.x;
    const int bid = (blockIdx.x & 7) * (4096 / 8) + (blockIdx.x >> 3);
    const int base = bid * RMBLK;
    const int batch = base >> 14;

    for (int i = t; i < RMBLK * 6; i += 256)
        ridx[i] = ring[(size_t)base * 6 + i];
    __syncthreads();

    {
        const int c2 = t & 63;
        const int fq = t >> 6;
        const float2* fb = (const float2*)feat + (size_t)batch * NFACE * 64;
        for (int it = 0; it < RMBLK / 4; ++it) {
            const int fl = it * 4 + fq;
            const int* ri = &ridx[fl * 6];
            float nl[6], nh[6];
#pragma unroll
            for (int j = 0; j < 6; ++j) {
                float2 u = fb[(size_t)ri[j] * 64 + c2];
                nl[j] = u.x; nh[j] = u.y;
            }
            float fc1l = nl[1] + nl[2] + nl[3] + nl[4] + nl[5];
            float fc1h = nh[1] + nh[2] + nh[3] + nh[4] + nh[5];
            float fc2l = fabsf(5.0f * nl[0] - fc1l);
            float fc2h = fabsf(5.0f * nh[0] - fc1h);
            float fc3l = 0.f, fc3h = 0.f;
#pragma unroll
            for (int a = 1; a < 5; ++a)
#pragma unroll
                for (int b = a + 1; b < 6; ++b) {
                    fc3l += fabsf(nl[a] - nl[b]);
                    fc3h += fabsf(nh[a] - nh[b]);
                }
            unsigned* row = (unsigned*)&fcv[fl * RLDF];
            row[c2]       = pack2bf(nl[0], nh[0]);
            row[64 + c2]  = pack2bf(fc1l, fc1h);
            row[128 + c2] = pack2bf(fc2l, fc2h);
            row[192 + c2] = pack2bf(fc3l, fc3h);
        }
    }
    __syncthreads();

    const int w  = t >> 6;
    const int l  = t & 63;
    const int lo = l & 15;
    const int hi = l >> 4;
    const int col0 = w * 32;

    f32x4 acc[2][2];
#pragma unroll
    for (int rt = 0; rt < 2; ++rt)
#pragma unroll
        for (int ct = 0; ct < 2; ++ct)
            acc[rt][ct] = (f32x4){0.f, 0.f, 0.f, 0.f};

    const unsigned short* __restrict__ wb0 = wbt + (size_t)(col0 + lo) * KGEMM;

    for (int ks = 0; ks < 16; ++ks) {
        const int k0 = ks * 32 + hi * 8;
        short8 a0 = *(const short8*)&fcv[(0 * 16 + lo) * RLDF + k0];
        short8 a1 = *(const short8*)&fcv[(1 * 16 + lo) * RLDF + k0];
        short8 b0 = *(const short8*)&wb0[k0];
        short8 b1 = *(const short8*)&wb0[16 * KGEMM + k0];
        acc[0][0] = __builtin_amdgcn_mfma_f32_16x16x32_bf16(a0, b0, acc[0][0], 0, 0, 0);
        acc[1][0] = __builtin_amdgcn_mfma_f32_16x16x32_bf16(a1, b0, acc[1][0], 0, 0, 0);
        acc[0][1] = __builtin_amdgcn_mfma_f32_16x16x32_bf16(a0, b1, acc[0][1], 0, 0, 0);
        acc[1][1] = __builtin_amdgcn_mfma_f32_16x16x32_bf16(a1, b1, acc[1][1], 0, 0, 0);
    }

    const float bo0 = bias[col0 + lo];
    const float bo1 = bias[col0 + 16 + lo];
#pragma unroll
    for (int rt = 0; rt < 2; ++rt) {
#pragma unroll
        for (int v = 0; v < 4; ++v) {
            const int r = base + rt * 16 + hi * 4 + v;
            out[(size_t)r * COUT + col0 + lo]      = acc[rt][0][v] + bo0;
            out[(size_t)r * COUT + col0 + 16 + lo] = acc[rt][1][v] + bo1;
        }
    }
}

__global__ void zero_kernel(const int* __restrict__ zm, const int* __restrict__ zf,
                            float* __restrict__ out) {
    const int i = blockIdx.x;
    const size_t face = (size_t)zm[i] * NFACE + zf[i];
    out[face * COUT + threadIdx.x] = 0.0f;
}

extern "C" void kernel_launch(void* const* d_in, const int* in_sizes, int n_in,
                              void* d_out, int out_size, void* d_ws, size_t ws_size,
                              hipStream_t stream) {
    const float* feat = (const float*)d_in[0];
    const int*   ring = (const int*)d_in[1];
    const float* wgt  = (const float*)d_in[2];
    const float* bias = (const float*)d_in[3];
    const int*   zm   = (const int*)d_in[4];
    const int*   zf   = (const int*)d_in[5];
    float* out = (float*)d_out;

    const size_t feath_bytes = (size_t)NBATCH * NFACE * CIN * 2;  // 32 MiB
    const size_t wbt_bytes = (size_t)COUT * KGEMM * 2;            // 128 KiB
    const bool use_f16 = ws_size >= feath_bytes + wbt_bytes;

    if (use_f16) {
        unsigned* feath = (unsigned*)d_ws;
        _Float16* wbt2 = (_Float16*)((char*)d_ws + feath_bytes);
        const int n4 = NBATCH * NFACE * CIN / 8;
        hipLaunchKernelGGL(fconv_kernel, dim3((n4 + 255) / 256), dim3(256), 0, stream,
                           feat, feath, n4);
        hipLaunchKernelGGL(wconv2_kernel, dim3((COUT * CIN + 255) / 256), dim3(256), 0, stream,
                           wgt, wbt2);
        hipLaunchKernelGGL(meshconv_v9, dim3(GRID), dim3(256), 0, stream,
                           feath, ring, wbt2, bias, out);
    } else {
        unsigned short* wbt = (unsigned short*)d_ws;
        hipLaunchKernelGGL(wconv_kernel, dim3((COUT * CIN + 255) / 256), dim3(256), 0, stream,
                           wgt, wbt);
        hipLaunchKernelGGL(meshconv_ref, dim3(4096), dim3(256), 0, stream,
                           feat, ring, wbt, bias, out);
    }
    hipLaunchKernelGGL(zero_kernel, dim3(1024), dim3(128), 0, stream, zm, zf, out);
}

// Round 10
// 64.660 us; speedup vs baseline: 1.9986x; 1.9986x over previous
//
#include <hip/hip_runtime.h>
#include <hip/hip_bf16.h>

typedef __attribute__((ext_vector_type(8))) short short8;
typedef __attribute__((ext_vector_type(8))) _Float16 half8;
typedef __attribute__((ext_vector_type(2))) _Float16 h2;
typedef __attribute__((ext_vector_type(4))) float f32x4;

#define NFACE 16384
#define NBATCH 8
#define CIN 128
#define COUT 128
#define KGEMM 512
#define MBLK 128                       // faces per block (4 iters of 32)
#define GRID ((NBATCH * NFACE) / MBLK) // 1024, divisible by 8
#define LDA 520                        // A row stride in halfs (512 + 8): lane bank spread as R7/R8

__device__ __forceinline__ unsigned short f2bf(float x) {
    union { float f; unsigned u; } v; v.f = x;
    unsigned r = v.u + 0x7fffu + ((v.u >> 16) & 1u);  // RNE
    return (unsigned short)(r >> 16);
}
__device__ __forceinline__ unsigned pack2bf(float lo, float hi) {
    return (unsigned)f2bf(lo) | ((unsigned)f2bf(hi) << 16);
}
__device__ __forceinline__ h2 habs2(h2 x) {
    union { h2 h; unsigned u; } v; v.h = x; v.u &= 0x7fff7fffu; return v.h;
}
__device__ __forceinline__ unsigned h2u(h2 x) {
    union { h2 h; unsigned u; } v; v.h = x; return v.u;
}
__device__ __forceinline__ h2 u2h(unsigned x) {
    union { h2 h; unsigned u; } v; v.u = x; return v.h;
}

// ---- features fp32 -> packed f16 (linear grid) ----
__global__ void fconv_kernel(const float* __restrict__ f, unsigned* __restrict__ o, int n4) {
    int i = blockIdx.x * 256 + threadIdx.x;  // one uint4 (8 floats -> 8 halfs)
    if (i >= n4) return;
    const float4* fp = (const float4*)f;
    float4 a = fp[i * 2], b = fp[i * 2 + 1];
    h2 p0 = {(_Float16)a.x, (_Float16)a.y};
    h2 p1 = {(_Float16)a.z, (_Float16)a.w};
    h2 p2 = {(_Float16)b.x, (_Float16)b.y};
    h2 p3 = {(_Float16)b.z, (_Float16)b.w};
    uint4 r; r.x = h2u(p0); r.y = h2u(p1); r.z = h2u(p2); r.w = h2u(p3);
    ((uint4*)o)[i] = r;
}

// ---- weight fp32 (o,c,1,4) -> f16, full-K kk-major: wbth[o][kk*128 + c] ----
__global__ void wconvh_kernel(const float* __restrict__ w, _Float16* __restrict__ bt) {
    int i = blockIdx.x * 256 + threadIdx.x;  // one (o,c) pair = 4 floats
    if (i >= COUT * CIN) return;
    int o = i >> 7, c = i & 127;
    float4 wv = ((const float4*)w)[i];
    _Float16* dst = bt + (size_t)o * KGEMM + c;
    dst[0]   = (_Float16)wv.x;
    dst[128] = (_Float16)wv.y;
    dst[256] = (_Float16)wv.z;
    dst[384] = (_Float16)wv.w;
}

// ---- old-layout bf16 weight (fallback path): bt[o][kk*128+c] ----
__global__ void wconv_kernel(const float* __restrict__ w, unsigned short* __restrict__ bt) {
    int i = blockIdx.x * 256 + threadIdx.x;
    if (i >= COUT * CIN) return;
    int o = i >> 7, c = i & 127;
#pragma unroll
    for (int kk = 0; kk < 4; ++kk)
        bt[o * KGEMM + kk * CIN + c] = f2bf(w[(o * CIN + c) * 4 + kk]);
}

// Build one face's 8-channel slice across full K (kk-major: K = kk*128 + c) into LDS.
// 6 coalesced 16-B gathers, packed-f16 math, loads consumed immediately (no regs
// held across MFMA — R5/R6 scratch-spill lesson).
__device__ __forceinline__ void build_iter(const char* __restrict__ fbb,
                                           const int* __restrict__ ri,  // 6 neighbor ids (LDS)
                                           int oct,
                                           _Float16* __restrict__ Arow) {
    uint4 n[6];
#pragma unroll
    for (int j = 0; j < 6; ++j)
        n[j] = *(const uint4*)(fbb + (size_t)(ri[j] * 256 + oct * 16));

    unsigned f1w[4], f2w[4], f3w[4];
#pragma unroll
    for (int q = 0; q < 4; ++q) {  // q = word = channels 2q,2q+1
        h2 x0 = u2h(((const unsigned*)&n[0])[q]);
        h2 x1 = u2h(((const unsigned*)&n[1])[q]);
        h2 x2 = u2h(((const unsigned*)&n[2])[q]);
        h2 x3 = u2h(((const unsigned*)&n[3])[q]);
        h2 x4 = u2h(((const unsigned*)&n[4])[q]);
        h2 x5 = u2h(((const unsigned*)&n[5])[q]);
        h2 s = x1 + x2; s = s + x3; s = s + x4; s = s + x5;
        h2 five = {(_Float16)5.0f, (_Float16)5.0f};
        h2 d = habs2(five * x0 - s);
        h2 t3 = habs2(x1 - x2) + habs2(x1 - x3);
        t3 = t3 + habs2(x1 - x4); t3 = t3 + habs2(x1 - x5);
        t3 = t3 + habs2(x2 - x3); t3 = t3 + habs2(x2 - x4);
        t3 = t3 + habs2(x2 - x5); t3 = t3 + habs2(x3 - x4);
        t3 = t3 + habs2(x3 - x5); t3 = t3 + habs2(x4 - x5);
        f1w[q] = h2u(s); f2w[q] = h2u(d); f3w[q] = h2u(t3);
    }
    // A-row layout: halfs [kk*128 + c], c = oct*8 .. +8
    *(uint4*)&Arow[0 * 128 + oct * 8] = n[0];
    *(uint4*)&Arow[1 * 128 + oct * 8] = (uint4){f1w[0], f1w[1], f1w[2], f1w[3]};
    *(uint4*)&Arow[2 * 128 + oct * 8] = (uint4){f2w[0], f2w[1], f2w[2], f2w[3]};
    *(uint4*)&Arow[3 * 128 + oct * 8] = (uint4){f3w[0], f3w[1], f3w[2], f3w[3]};
}

// v10: weight-stationary in registers (16 half8 = 64 VGPR per wave, loaded once),
// A double-buffered in LDS (32 faces x K512), one barrier per 32-face iteration,
// full-K GEMM per iteration, store immediately (acc = 8 VGPR). No W LDS at all.
__global__ __launch_bounds__(512, 4)
void meshconv_v10(const unsigned* __restrict__ featf16,
                  const int* __restrict__ ring,
                  const _Float16* __restrict__ wbth,
                  const float* __restrict__ bias,
                  float* __restrict__ out)
{
    __shared__ _Float16 Abuf[2][32 * LDA];  // 2 x 32.5 KiB
    __shared__ int ridx[MBLK * 6];          // 3 KiB

    const int t = threadIdx.x;
    // batch-per-XCD swizzle: 128 blocks per batch, one batch per XCD
    const int bid = (blockIdx.x & 7) * (GRID / 8) + (blockIdx.x >> 3);
    const int base = bid * MBLK;
    const int batch = bid >> 7;

    if (t < 192)  // 128 faces * 6 ints = 192 uint4
        ((uint4*)ridx)[t] = ((const uint4*)(ring + (size_t)base * 6))[t];

    // GEMM mapping: 8 waves x 16 cols each
    const int w  = t >> 6;
    const int l  = t & 63;
    const int lo = l & 15;
    const int hi = l >> 4;
    const int col0 = w * 16;

    // ---- B preload: full K for this wave's 16 cols, once (L2, 128 KB/block) ----
    half8 B[16];
    {
        const _Float16* wb = wbth + (size_t)(col0 + lo) * KGEMM + hi * 8;
#pragma unroll
        for (int ks = 0; ks < 16; ++ks)
            B[ks] = *(const half8*)&wb[ks * 32];
    }
    const float bo = bias[col0 + lo];

    // build mapping: thread = (face bf = t>>4 within 32, channel-octet oct = t&15)
    const int bf  = t >> 4;
    const int oct = t & 15;
    const char* __restrict__ fbb = (const char*)featf16 + (size_t)batch * NFACE * 256;

    __syncthreads();  // ridx ready

    build_iter(fbb, &ridx[bf * 6], oct, &Abuf[0][bf * LDA]);

    for (int i = 0; i < 4; ++i) {
        __syncthreads();  // Abuf[i&1] complete; Abuf[(i+1)&1] free (prev GEMM done)

        if (i < 3)
            build_iter(fbb, &ridx[((i + 1) * 32 + bf) * 6], oct,
                       &Abuf[(i + 1) & 1][bf * LDA]);

        // ---- GEMM: 32 faces x 16 cols, full K=512 ----
        f32x4 acc0 = (f32x4){0.f, 0.f, 0.f, 0.f};
        f32x4 acc1 = (f32x4){0.f, 0.f, 0.f, 0.f};
        const _Float16* __restrict__ Ab = &Abuf[i & 1][0];
#pragma unroll
        for (int ks = 0; ks < 16; ++ks) {
            const int k0 = ks * 32 + hi * 8;
            half8 a0 = *(const half8*)&Ab[lo * LDA + k0];
            half8 a1 = *(const half8*)&Ab[(16 + lo) * LDA + k0];
            acc0 = __builtin_amdgcn_mfma_f32_16x16x32_f16(a0, B[ks], acc0, 0, 0, 0);
            acc1 = __builtin_amdgcn_mfma_f32_16x16x32_f16(a1, B[ks], acc1, 0, 0, 0);
        }

        // ---- store these 32 faces (full K done) ----
#pragma unroll
        for (int v = 0; v < 4; ++v) {
            const int r0 = base + i * 32 + hi * 4 + v;       // C/D: row=(l>>4)*4+v, col=l&15
            out[(size_t)r0 * COUT + col0 + lo]        = acc0[v] + bo;
            out[(size_t)(r0 + 16) * COUT + col0 + lo] = acc1[v] + bo;
        }
    }
}

// fallback (ws too small): fp32 gather, bf16 MFMA, old weight layout
__global__ __launch_bounds__(256, 4)
void meshconv_ref(const float* __restrict__ feat,
                  const int* __restrict__ ring,
                  const unsigned short* __restrict__ wbt,
                  const float* __restrict__ bias,
                  float* __restrict__ out)
{
#define RMBLK 32
#define RLDF 520
    __shared__ unsigned short fcv[RMBLK * RLDF];
    __shared__ int ridx[RMBLK * 6];

    const int t = threadIdx.x;
    const int bid = (blockIdx.x & 7) * (4096 / 8) + (blockIdx.x >> 3);
    const int base = bid * RMBLK;
    const int batch = base >> 14;

    for (int i = t; i < RMBLK * 6; i += 256)
        ridx[i] = ring[(size_t)base * 6 + i];
    __syncthreads();

    {
        const int c2 = t & 63;
        const int fq = t >> 6;
        const float2* fb = (const float2*)feat + (size_t)batch * NFACE * 64;
        for (int it = 0; it < RMBLK / 4; ++it) {
            const int fl = it * 4 + fq;
            const int* ri = &ridx[fl * 6];
            float nl[6], nh[6];
#pragma unroll
            for (int j = 0; j < 6; ++j) {
                float2 u = fb[(size_t)ri[j] * 64 + c2];
                nl[j] = u.x; nh[j] = u.y;
            }
            float fc1l = nl[1] + nl[2] + nl[3] + nl[4] + nl[5];
            float fc1h = nh[1] + nh[2] + nh[3] + nh[4] + nh[5];
            float fc2l = fabsf(5.0f * nl[0] - fc1l);
            float fc2h = fabsf(5.0f * nh[0] - fc1h);
            float fc3l = 0.f, fc3h = 0.f;
#pragma unroll
            for (int a = 1; a < 5; ++a)
#pragma unroll
                for (int b = a + 1; b < 6; ++b) {
                    fc3l += fabsf(nl[a] - nl[b]);
                    fc3h += fabsf(nh[a] - nh[b]);
                }
            unsigned* row = (unsigned*)&fcv[fl * RLDF];
            row[c2]       = pack2bf(nl[0], nh[0]);
            row[64 + c2]  = pack2bf(fc1l, fc1h);
            row[128 + c2] = pack2bf(fc2l, fc2h);
            row[192 + c2] = pack2bf(fc3l, fc3h);
        }
    }
    __syncthreads();

    const int w  = t >> 6;
    const int l  = t & 63;
    const int lo = l & 15;
    const int hi = l >> 4;
    const int col0 = w * 32;

    f32x4 acc[2][2];
#pragma unroll
    for (int rt = 0; rt < 2; ++rt)
#pragma unroll
        for (int ct = 0; ct < 2; ++ct)
            acc[rt][ct] = (f32x4){0.f, 0.f, 0.f, 0.f};

    const unsigned short* __restrict__ wb0 = wbt + (size_t)(col0 + lo) * KGEMM;

    for (int ks = 0; ks < 16; ++ks) {
        const int k0 = ks * 32 + hi * 8;
        short8 a0 = *(const short8*)&fcv[(0 * 16 + lo) * RLDF + k0];
        short8 a1 = *(const short8*)&fcv[(1 * 16 + lo) * RLDF + k0];
        short8 b0 = *(const short8*)&wb0[k0];
        short8 b1 = *(const short8*)&wb0[16 * KGEMM + k0];
        acc[0][0] = __builtin_amdgcn_mfma_f32_16x16x32_bf16(a0, b0, acc[0][0], 0, 0, 0);
        acc[1][0] = __builtin_amdgcn_mfma_f32_16x16x32_bf16(a1, b0, acc[1][0], 0, 0, 0);
        acc[0][1] = __builtin_amdgcn_mfma_f32_16x16x32_bf16(a0, b1, acc[0][1], 0, 0, 0);
        acc[1][1] = __builtin_amdgcn_mfma_f32_16x16x32_bf16(a1, b1, acc[1][1], 0, 0, 0);
    }

    const float bo0 = bias[col0 + lo];
    const float bo1 = bias[col0 + 16 + lo];
#pragma unroll
    for (int rt = 0; rt < 2; ++rt) {
#pragma unroll
        for (int v = 0; v < 4; ++v) {
            const int r = base + rt * 16 + hi * 4 + v;
            out[(size_t)r * COUT + col0 + lo]      = acc[rt][0][v] + bo0;
            out[(size_t)r * COUT + col0 + 16 + lo] = acc[rt][1][v] + bo1;
        }
    }
}

__global__ void zero_kernel(const int* __restrict__ zm, const int* __restrict__ zf,
                            float* __restrict__ out) {
    const int i = blockIdx.x;
    const size_t face = (size_t)zm[i] * NFACE + zf[i];
    out[face * COUT + threadIdx.x] = 0.0f;
}

extern "C" void kernel_launch(void* const* d_in, const int* in_sizes, int n_in,
                              void* d_out, int out_size, void* d_ws, size_t ws_size,
                              hipStream_t stream) {
    const float* feat = (const float*)d_in[0];
    const int*   ring = (const int*)d_in[1];
    const float* wgt  = (const float*)d_in[2];
    const float* bias = (const float*)d_in[3];
    const int*   zm   = (const int*)d_in[4];
    const int*   zf   = (const int*)d_in[5];
    float* out = (float*)d_out;

    const size_t feath_bytes = (size_t)NBATCH * NFACE * CIN * 2;  // 32 MiB
    const size_t wbt_bytes = (size_t)COUT * KGEMM * 2;            // 128 KiB
    const bool use_f16 = ws_size >= feath_bytes + wbt_bytes;

    if (use_f16) {
        unsigned* feath = (unsigned*)d_ws;
        _Float16* wbth = (_Float16*)((char*)d_ws + feath_bytes);
        const int n4 = NBATCH * NFACE * CIN / 8;
        hipLaunchKernelGGL(fconv_kernel, dim3((n4 + 255) / 256), dim3(256), 0, stream,
                           feat, feath, n4);
        hipLaunchKernelGGL(wconvh_kernel, dim3((COUT * CIN + 255) / 256), dim3(256), 0, stream,
                           wgt, wbth);
        hipLaunchKernelGGL(meshconv_v10, dim3(GRID), dim3(512), 0, stream,
                           feath, ring, wbth, bias, out);
    } else {
        unsigned short* wbt = (unsigned short*)d_ws;
        hipLaunchKernelGGL(wconv_kernel, dim3((COUT * CIN + 255) / 256), dim3(256), 0, stream,
                           wgt, wbt);
        hipLaunchKernelGGL(meshconv_ref, dim3(4096), dim3(256), 0, stream,
                           feat, ring, wbt, bias, out);
    }
    hipLaunchKernelGGL(zero_kernel, dim3(1024), dim3(128), 0, stream, zm, zf, out);
}

// Round 11
// 60.046 us; speedup vs baseline: 2.1522x; 1.0768x over previous
//
#include <hip/hip_runtime.h>
#include <hip/hip_bf16.h>

typedef __attribute__((ext_vector_type(8))) short short8;
typedef __attribute__((ext_vector_type(8))) _Float16 half8;
typedef __attribute__((ext_vector_type(2))) _Float16 h2;
typedef __attribute__((ext_vector_type(4))) float f32x4;
typedef __attribute__((ext_vector_type(4))) unsigned uintx4;

#define NFACE 16384
#define NBATCH 8
#define CIN 128
#define COUT 128
#define KGEMM 512
#define TFACE 32                        // faces per tile
#define NTILE 8                         // tiles per block
#define MBLK (TFACE * NTILE)            // 256 faces per block
#define GRID ((NBATCH * NFACE) / MBLK)  // 512, divisible by 8
#define LDA 520                         // A row stride in halfs (512 + 8)

__device__ __forceinline__ unsigned short f2bf(float x) {
    union { float f; unsigned u; } v; v.f = x;
    unsigned r = v.u + 0x7fffu + ((v.u >> 16) & 1u);  // RNE
    return (unsigned short)(r >> 16);
}
__device__ __forceinline__ unsigned pack2bf(float lo, float hi) {
    return (unsigned)f2bf(lo) | ((unsigned)f2bf(hi) << 16);
}
__device__ __forceinline__ h2 habs2(h2 x) {
    union { h2 h; unsigned u; } v; v.h = x; v.u &= 0x7fff7fffu; return v.h;
}
__device__ __forceinline__ unsigned h2u(h2 x) {
    union { h2 h; unsigned u; } v; v.h = x; return v.u;
}
__device__ __forceinline__ h2 u2h(unsigned x) {
    union { h2 h; unsigned u; } v; v.u = x; return v.h;
}

// ---- features fp32 -> packed f16 (linear grid) ----
__global__ void fconv_kernel(const float* __restrict__ f, unsigned* __restrict__ o, int n4) {
    int i = blockIdx.x * 256 + threadIdx.x;  // one uint4 (8 floats -> 8 halfs)
    if (i >= n4) return;
    const float4* fp = (const float4*)f;
    float4 a = fp[i * 2], b = fp[i * 2 + 1];
    h2 p0 = {(_Float16)a.x, (_Float16)a.y};
    h2 p1 = {(_Float16)a.z, (_Float16)a.w};
    h2 p2 = {(_Float16)b.x, (_Float16)b.y};
    h2 p3 = {(_Float16)b.z, (_Float16)b.w};
    uint4 r; r.x = h2u(p0); r.y = h2u(p1); r.z = h2u(p2); r.w = h2u(p3);
    ((uint4*)o)[i] = r;
}

// ---- weight fp32 (o,c,1,4) -> f16, full-K kk-major: wbth[o][kk*128 + c] ----
__global__ void wconvh_kernel(const float* __restrict__ w, _Float16* __restrict__ bt) {
    int i = blockIdx.x * 256 + threadIdx.x;  // one (o,c) pair = 4 floats
    if (i >= COUT * CIN) return;
    int o = i >> 7, c = i & 127;
    float4 wv = ((const float4*)w)[i];
    _Float16* dst = bt + (size_t)o * KGEMM + c;
    dst[0]   = (_Float16)wv.x;
    dst[128] = (_Float16)wv.y;
    dst[256] = (_Float16)wv.z;
    dst[384] = (_Float16)wv.w;
}

// ---- old-layout bf16 weight (fallback path): bt[o][kk*128+c] ----
__global__ void wconv_kernel(const float* __restrict__ w, unsigned short* __restrict__ bt) {
    int i = blockIdx.x * 256 + threadIdx.x;
    if (i >= COUT * CIN) return;
    int o = i >> 7, c = i & 127;
#pragma unroll
    for (int kk = 0; kk < 4; ++kk)
        bt[o * KGEMM + kk * CIN + c] = f2bf(w[(o * CIN + c) * 4 + kk]);
}

// Build one face's 8-channel octet across full K (kk-major: K = kk*128 + c) into LDS.
// 6 coalesced 16-B gathers, packed-f16 math, loads consumed immediately.
__device__ __forceinline__ void build_iter(const char* __restrict__ fbb,
                                           const int* __restrict__ ri,  // 6 neighbor ids (LDS)
                                           int oct,
                                           _Float16* __restrict__ Arow) {
    uint4 n[6];
#pragma unroll
    for (int j = 0; j < 6; ++j)
        n[j] = *(const uint4*)(fbb + (size_t)(ri[j] * 256 + oct * 16));

    unsigned f1w[4], f2w[4], f3w[4];
#pragma unroll
    for (int q = 0; q < 4; ++q) {  // q = word = channels 2q,2q+1
        h2 x0 = u2h(((const unsigned*)&n[0])[q]);
        h2 x1 = u2h(((const unsigned*)&n[1])[q]);
        h2 x2 = u2h(((const unsigned*)&n[2])[q]);
        h2 x3 = u2h(((const unsigned*)&n[3])[q]);
        h2 x4 = u2h(((const unsigned*)&n[4])[q]);
        h2 x5 = u2h(((const unsigned*)&n[5])[q]);
        h2 s = x1 + x2; s = s + x3; s = s + x4; s = s + x5;
        h2 five = {(_Float16)5.0f, (_Float16)5.0f};
        h2 d = habs2(five * x0 - s);
        h2 t3 = habs2(x1 - x2) + habs2(x1 - x3);
        t3 = t3 + habs2(x1 - x4); t3 = t3 + habs2(x1 - x5);
        t3 = t3 + habs2(x2 - x3); t3 = t3 + habs2(x2 - x4);
        t3 = t3 + habs2(x2 - x5); t3 = t3 + habs2(x3 - x4);
        t3 = t3 + habs2(x3 - x5); t3 = t3 + habs2(x4 - x5);
        f1w[q] = h2u(s); f2w[q] = h2u(d); f3w[q] = h2u(t3);
    }
    // A-row layout: halfs [kk*128 + c], c = oct*8 .. +8
    *(uint4*)&Arow[0 * 128 + oct * 8] = n[0];
    *(uint4*)&Arow[1 * 128 + oct * 8] = (uint4){f1w[0], f1w[1], f1w[2], f1w[3]};
    *(uint4*)&Arow[2 * 128 + oct * 8] = (uint4){f2w[0], f2w[1], f2w[2], f2w[3]};
    *(uint4*)&Arow[3 * 128 + oct * 8] = (uint4){f3w[0], f3w[1], f3w[2], f3w[3]};
}

// v11: B truly register-stationary — 32 x uintx4 = 128 VGPR per wave (32 cols x K512),
// asm-pinned so the allocator cannot sink the loads (v10 lesson: VGPR=64 proved it
// rematerialized B from L2 every iteration). A transits LDS, read by only 4 col-waves.
// 256 threads = 4 waves; 8 tiles of 32 faces; 2 barriers per tile.
__global__ __launch_bounds__(256, 2)
void meshconv_v11(const unsigned* __restrict__ featf16,
                  const int* __restrict__ ring,
                  const _Float16* __restrict__ wbth,
                  const float* __restrict__ bias,
                  float* __restrict__ out)
{
    __shared__ _Float16 Al[TFACE * LDA];  // 33 KiB
    __shared__ int ridx[MBLK * 6];        // 6 KiB

    const int t = threadIdx.x;
    // batch-per-XCD swizzle: 64 blocks per batch, one batch per XCD
    const int bid = (blockIdx.x & 7) * (GRID / 8) + (blockIdx.x >> 3);
    const int base = bid * MBLK;
    const int batch = bid >> 6;

    for (int i = t; i < MBLK * 6 / 4; i += 256)   // 384 uint4
        ((uint4*)ridx)[i] = ((const uint4*)(ring + (size_t)base * 6))[i];

    const int w  = t >> 6;   // wave = col-group: cols [w*32, w*32+32)
    const int l  = t & 63;
    const int lo = l & 15;
    const int hi = l >> 4;
    const int col0 = w * 32;

    // ---- B preload: 32 cols x full K, once per block (L2), then PIN ----
    uintx4 B[2][16];
    {
        const _Float16* wb = wbth + (size_t)(col0 + lo) * KGEMM + hi * 8;
#pragma unroll
        for (int ct = 0; ct < 2; ++ct)
#pragma unroll
            for (int ks = 0; ks < 16; ++ks)
                B[ct][ks] = *(const uintx4*)&wb[(size_t)(ct * 16) * KGEMM + ks * 32];
    }
#pragma unroll
    for (int ct = 0; ct < 2; ++ct)
#pragma unroll
        for (int ks = 0; ks < 16; ++ks)
            asm volatile("" : "+v"(B[ct][ks]));   // forbid remat/sink of B loads

    const float bo0 = bias[col0 + lo];
    const float bo1 = bias[col0 + 16 + lo];

    // build mapping: thread = (face f = t>>3, oc = t&7 -> octets 2oc, 2oc+1)
    const int f  = t >> 3;
    const int oc = t & 7;
    const char* __restrict__ fbb = (const char*)featf16 + (size_t)batch * NFACE * 256;

    __syncthreads();  // ridx ready

    for (int tile = 0; tile < NTILE; ++tile) {
        if (tile) __syncthreads();  // prev GEMM's A reads done

        const int* ri = &ridx[(tile * TFACE + f) * 6];
        build_iter(fbb, ri, oc * 2,     &Al[f * LDA]);
        build_iter(fbb, ri, oc * 2 + 1, &Al[f * LDA]);
        __syncthreads();

        // ---- GEMM: 32 faces x 32 cols, full K=512, B from registers ----
        f32x4 acc[2][2];
#pragma unroll
        for (int rt = 0; rt < 2; ++rt)
#pragma unroll
            for (int ct = 0; ct < 2; ++ct)
                acc[rt][ct] = (f32x4){0.f, 0.f, 0.f, 0.f};

#pragma unroll
        for (int ks = 0; ks < 16; ++ks) {
            const int k0 = ks * 32 + hi * 8;
            half8 a0 = *(const half8*)&Al[lo * LDA + k0];
            half8 a1 = *(const half8*)&Al[(16 + lo) * LDA + k0];
            half8 b0 = __builtin_bit_cast(half8, B[0][ks]);
            half8 b1 = __builtin_bit_cast(half8, B[1][ks]);
            acc[0][0] = __builtin_amdgcn_mfma_f32_16x16x32_f16(a0, b0, acc[0][0], 0, 0, 0);
            acc[1][0] = __builtin_amdgcn_mfma_f32_16x16x32_f16(a1, b0, acc[1][0], 0, 0, 0);
            acc[0][1] = __builtin_amdgcn_mfma_f32_16x16x32_f16(a0, b1, acc[0][1], 0, 0, 0);
            acc[1][1] = __builtin_amdgcn_mfma_f32_16x16x32_f16(a1, b1, acc[1][1], 0, 0, 0);
        }

        // ---- store this tile (full K done) ----
#pragma unroll
        for (int rt = 0; rt < 2; ++rt) {
#pragma unroll
            for (int v = 0; v < 4; ++v) {
                const int r = base + tile * TFACE + rt * 16 + hi * 4 + v;  // row=(l>>4)*4+v, col=l&15
                out[(size_t)r * COUT + col0 + lo]      = acc[rt][0][v] + bo0;
                out[(size_t)r * COUT + col0 + 16 + lo] = acc[rt][1][v] + bo1;
            }
        }
    }
}

// fallback (ws too small): fp32 gather, bf16 MFMA, old weight layout
__global__ __launch_bounds__(256, 4)
void meshconv_ref(const float* __restrict__ feat,
                  const int* __restrict__ ring,
                  const unsigned short* __restrict__ wbt,
                  const float* __restrict__ bias,
                  float* __restrict__ out)
{
#define RMBLK 32
#define RLDF 520
    __shared__ unsigned short fcv[RMBLK * RLDF];
    __shared__ int ridx[RMBLK * 6];

    const int t = threadIdx.x;
    const int bid = (blockIdx.x & 7) * (4096 / 8) + (blockIdx.x >> 3);
    const int base = bid * RMBLK;
    const int batch = base >> 14;

    for (int i = t; i < RMBLK * 6; i += 256)
        ridx[i] = ring[(size_t)base * 6 + i];
    __syncthreads();

    {
        const int c2 = t & 63;
        const int fq = t >> 6;
        const float2* fb = (const float2*)feat + (size_t)batch * NFACE * 64;
        for (int it = 0; it < RMBLK / 4; ++it) {
            const int fl = it * 4 + fq;
            const int* ri = &ridx[fl * 6];
            float nl[6], nh[6];
#pragma unroll
            for (int j = 0; j < 6; ++j) {
                float2 u = fb[(size_t)ri[j] * 64 + c2];
                nl[j] = u.x; nh[j] = u.y;
            }
            float fc1l = nl[1] + nl[2] + nl[3] + nl[4] + nl[5];
            float fc1h = nh[1] + nh[2] + nh[3] + nh[4] + nh[5];
            float fc2l = fabsf(5.0f * nl[0] - fc1l);
            float fc2h = fabsf(5.0f * nh[0] - fc1h);
            float fc3l = 0.f, fc3h = 0.f;
#pragma unroll
            for (int a = 1; a < 5; ++a)
#pragma unroll
                for (int b = a + 1; b < 6; ++b) {
                    fc3l += fabsf(nl[a] - nl[b]);
                    fc3h += fabsf(nh[a] - nh[b]);
                }
            unsigned* row = (unsigned*)&fcv[fl * RLDF];
            row[c2]       = pack2bf(nl[0], nh[0]);
            row[64 + c2]  = pack2bf(fc1l, fc1h);
            row[128 + c2] = pack2bf(fc2l, fc2h);
            row[192 + c2] = pack2bf(fc3l, fc3h);
        }
    }
    __syncthreads();

    const int w  = t >> 6;
    const int l  = t & 63;
    const int lo = l & 15;
    const int hi = l >> 4;
    const int col0 = w * 32;

    f32x4 acc[2][2];
#pragma unroll
    for (int rt = 0; rt < 2; ++rt)
#pragma unroll
        for (int ct = 0; ct < 2; ++ct)
            acc[rt][ct] = (f32x4){0.f, 0.f, 0.f, 0.f};

    const unsigned short* __restrict__ wb0 = wbt + (size_t)(col0 + lo) * KGEMM;

    for (int ks = 0; ks < 16; ++ks) {
        const int k0 = ks * 32 + hi * 8;
        short8 a0 = *(const short8*)&fcv[(0 * 16 + lo) * RLDF + k0];
        short8 a1 = *(const short8*)&fcv[(1 * 16 + lo) * RLDF + k0];
        short8 b0 = *(const short8*)&wb0[k0];
        short8 b1 = *(const short8*)&wb0[16 * KGEMM + k0];
        acc[0][0] = __builtin_amdgcn_mfma_f32_16x16x32_bf16(a0, b0, acc[0][0], 0, 0, 0);
        acc[1][0] = __builtin_amdgcn_mfma_f32_16x16x32_bf16(a1, b0, acc[1][0], 0, 0, 0);
        acc[0][1] = __builtin_amdgcn_mfma_f32_16x16x32_bf16(a0, b1, acc[0][1], 0, 0, 0);
        acc[1][1] = __builtin_amdgcn_mfma_f32_16x16x32_bf16(a1, b1, acc[1][1], 0, 0, 0);
    }

    const float bo0 = bias[col0 + lo];
    const float bo1 = bias[col0 + 16 + lo];
#pragma unroll
    for (int rt = 0; rt < 2; ++rt) {
#pragma unroll
        for (int v = 0; v < 4; ++v) {
            const int r = base + rt * 16 + hi * 4 + v;
            out[(size_t)r * COUT + col0 + lo]      = acc[rt][0][v] + bo0;
            out[(size_t)r * COUT + col0 + 16 + lo] = acc[rt][1][v] + bo1;
        }
    }
}

__global__ void zero_kernel(const int* __restrict__ zm, const int* __restrict__ zf,
                            float* __restrict__ out) {
    const int i = blockIdx.x;
    const size_t face = (size_t)zm[i] * NFACE + zf[i];
    out[face * COUT + threadIdx.x] = 0.0f;
}

extern "C" void kernel_launch(void* const* d_in, const int* in_sizes, int n_in,
                              void* d_out, int out_size, void* d_ws, size_t ws_size,
                              hipStream_t stream) {
    const float* feat = (const float*)d_in[0];
    const int*   ring = (const int*)d_in[1];
    const float* wgt  = (const float*)d_in[2];
    const float* bias = (const float*)d_in[3];
    const int*   zm   = (const int*)d_in[4];
    const int*   zf   = (const int*)d_in[5];
    float* out = (float*)d_out;

    const size_t feath_bytes = (size_t)NBATCH * NFACE * CIN * 2;  // 32 MiB
    const size_t wbt_bytes = (size_t)COUT * KGEMM * 2;            // 128 KiB
    const bool use_f16 = ws_size >= feath_bytes + wbt_bytes;

    if (use_f16) {
        unsigned* feath = (unsigned*)d_ws;
        _Float16* wbth = (_Float16*)((char*)d_ws + feath_bytes);
        const int n4 = NBATCH * NFACE * CIN / 8;
        hipLaunchKernelGGL(fconv_kernel, dim3((n4 + 255) / 256), dim3(256), 0, stream,
                           feat, feath, n4);
        hipLaunchKernelGGL(wconvh_kernel, dim3((COUT * CIN + 255) / 256), dim3(256), 0, stream,
                           wgt, wbth);
        hipLaunchKernelGGL(meshconv_v11, dim3(GRID), dim3(256), 0, stream,
                           feath, ring, wbth, bias, out);
    } else {
        unsigned short* wbt = (unsigned short*)d_ws;
        hipLaunchKernelGGL(wconv_kernel, dim3((COUT * CIN + 255) / 256), dim3(256), 0, stream,
                           wgt, wbt);
        hipLaunchKernelGGL(meshconv_ref, dim3(4096), dim3(256), 0, stream,
                           feat, ring, wbt, bias, out);
    }
    hipLaunchKernelGGL(zero_kernel, dim3(1024), dim3(128), 0, stream, zm, zf, out);
}